// Round 8
// baseline (159.835 us; speedup 1.0000x reference)
//
#include <hip/hip_runtime.h>
#include <hip/hip_bf16.h>

#define B_  8
#define T_  2048
#define E_  1024
#define H_  64
#define BT_ (B_*T_)

typedef __attribute__((ext_vector_type(8))) __bf16 bf16x8;
typedef __attribute__((ext_vector_type(4))) float  f32x4;

__device__ __forceinline__ unsigned short f2bfu(float f) {
    union { float f; unsigned u; } v; v.f = f;
    unsigned r = v.u + 0x7fffu + ((v.u >> 16) & 1u);
    return (unsigned short)(r >> 16);
}

__device__ __forceinline__ unsigned pk2(float lo, float hi) {
    __hip_bfloat162 h = __float22bfloat162_rn(float2{lo, hi});
    union { __hip_bfloat162 h; unsigned u; } v; v.h = h;
    return v.u;
}

// async global->LDS DMA, 16B/lane. LDS side is wave-uniform base; HW writes
// lane i at base + i*16 (m104). Global side is per-lane (gather).
#if defined(__has_builtin)
#if __has_builtin(__builtin_amdgcn_global_load_lds)
#define HAVE_GLL 1
#endif
#endif
__device__ __forceinline__ void dma16(const void* g, void* lds_base, int lane) {
#ifdef HAVE_GLL
    __builtin_amdgcn_global_load_lds(
        (const __attribute__((address_space(1))) unsigned*)(unsigned long long)g,
        (__attribute__((address_space(3))) unsigned*)(unsigned)(unsigned long long)lds_base,
        16, 0, 0);
#else
    *(uint4*)((char*)lds_base + lane * 16) = *(const uint4*)g;
#endif
}

// Q pre-scale: 1/sqrt(H) * log2(e)  (attn softmax runs in exp2 domain)
#define QSCALE (0.125f * 1.44269504f)

// wf chunk byte size: 3 mats * 4 n-tiles * 64 lanes * 16 B = 12288 B
#define WF_CHUNK_BYTES 12288

// ---------------- Phase 0: W -> fragment-major swizzled W^T (bf16) ----------
// wf layout: [c(32 k-chunks)][m(3)][n(4 h-tiles)][lane(64)][j(8)]
__global__ __launch_bounds__(256)
void wprep_kernel(const float* __restrict__ Wq,
                  const float* __restrict__ Wk,
                  const float* __restrict__ Wv,
                  unsigned short* __restrict__ wf)
{
    const int c = blockIdx.x / 3;
    const int m = blockIdx.x % 3;
    const float* W = (m == 0) ? Wq : (m == 1 ? Wk : Wv);
    const float scale = (m == 0) ? QSCALE : 1.0f;

    const int n    = threadIdx.x >> 6;
    const int lane = threadIdx.x & 63;
    const int quad = lane >> 4;
    const int col  = lane & 15;
    const int h    = n * 16 + col;

    unsigned short tmp[8];
#pragma unroll
    for (int j = 0; j < 8; ++j)
        tmp[j] = f2bfu(W[(c * 32 + quad * 8 + j) * H_ + h] * scale);
    *(uint4*)&wf[(((c * 3 + m) * 4 + n) * 64 + lane) * 8] = *(uint4*)tmp;
}

// ---------------- Phase 1: QKV projection (all-DMA double-buffer) ----------
// Block = 16 tokens, 4 waves; wave w owns h-tile w for all 3 matrices.
// Per 32-k chunk BOTH operands arrive by global_load_lds:
//   wf: 12 KB bf16 fragments (3 dma16/wave)
//   x : 2 KB fp32, XOR-swizzled on the global side so the 128B-stride
//       read back is only 2-way bank-aliased (free). A-frag rebuilt at
//       read: 2x ds_read_b128 fp32 + v_cvt_pk -> bf16x8.
__global__ __launch_bounds__(256, 4)
void qkv_kernel(const float* __restrict__ x,
                const unsigned short* __restrict__ wf,
                unsigned short* __restrict__ qb,
                unsigned short* __restrict__ kb,
                unsigned short* __restrict__ vtb)
{
    __shared__ __align__(16) char  wfs[2][WF_CHUNK_BYTES];   // 24 KB
    __shared__ __align__(16) float xs[2][512];               // 2 x 2 KB

    const int tid  = threadIdx.x;
    const int w    = tid >> 6;
    const int lane = tid & 63;
    const int quad = lane >> 4;
    const int col  = lane & 15;
    const long r0  = (long)blockIdx.x * 16;

    f32x4 acc[3];
#pragma unroll
    for (int m = 0; m < 3; ++m) acc[m] = (f32x4){0.f, 0.f, 0.f, 0.f};

    const char* wfb = (const char*)wf;

    // x DMA source for this lane (waves 0,1 only): token = w*8 + (lane>>3),
    // fetched 16B piece = (lane&7) ^ (lane>>3 & 7)  => LDS slot s of token t
    // holds piece s^(t&7).
    const float* xg = x + (r0 + w * 8 + (lane >> 3)) * E_ + (((lane & 7) ^ (lane >> 3)) * 4);

    // A-frag read slots for this lane (XOR-deswizzle)
    const int s0 = (2 * quad) ^ (col & 7);
    const int s1 = s0 ^ 1;

    // prologue: DMA chunk 0
#pragma unroll
    for (int j = 0; j < 3; ++j)
        dma16(wfb + (w * 3 + j) * 1024 + lane * 16, &wfs[0][(w * 3 + j) * 1024], lane);
    if (w < 2) dma16(xg, &xs[0][w * 256], lane);

    for (int c = 0; c < 32; ++c) {
        const int buf = c & 1;
        __syncthreads();                 // drains DMA(c)

        if (c + 1 < 32) {                // DMA c+1: one compute-phase of slack
#pragma unroll
            for (int j = 0; j < 3; ++j)
                dma16(wfb + (long)(c + 1) * WF_CHUNK_BYTES + (w * 3 + j) * 1024 + lane * 16,
                      &wfs[buf ^ 1][(w * 3 + j) * 1024], lane);
            if (w < 2) dma16(xg + (c + 1) * 32, &xs[buf ^ 1][w * 256], lane);
        }

        // rebuild A-fragment: token=col, k=quad*8..quad*8+7 (fp32 -> bf16)
        float4 f0 = *(const float4*)&xs[buf][col * 32 + s0 * 4];
        float4 f1 = *(const float4*)&xs[buf][col * 32 + s1 * 4];
        unsigned pk[4];
        pk[0] = pk2(f0.x, f0.y);
        pk[1] = pk2(f0.z, f0.w);
        pk[2] = pk2(f1.x, f1.y);
        pk[3] = pk2(f1.z, f1.w);
        bf16x8 af = *(bf16x8*)pk;

#pragma unroll
        for (int m = 0; m < 3; ++m) {
            bf16x8 bm = *(const bf16x8*)&wfs[buf][m * 4096 + w * 1024 + lane * 16];
            acc[m] = __builtin_amdgcn_mfma_f32_16x16x32_bf16(af, bm, acc[m], 0, 0, 0);
        }
    }

    // epilogue: D layout col=lane&15 (h-local), row=quad*4+reg (token)
    const int bidx = (int)(r0 >> 11);
    const int h    = w * 16 + col;
#pragma unroll
    for (int r = 0; r < 4; ++r) {
        long t = r0 + quad * 4 + r;
        qb[t * H_ + h] = f2bfu(acc[0][r]);        // scale folded into Wq
        kb[t * H_ + h] = f2bfu(acc[1][r]);
        vtb[((long)(bidx * H_ + h)) * T_ + (t & (T_ - 1))] = f2bfu(acc[2][r]);
    }
}

// ---------------- Phase 2: split-K flash attention ----------------
// Block = (batch, pair p): q-tiles p and 127-p (16 rows each), sequential.
// 8 waves = 8 split-K groups; wave g handles key-tiles s = g, g+8, ...
// K prefetched one tile ahead; V hoisted above softmax.
#define PSS 72

__global__ __launch_bounds__(512, 2)
void attn_kernel(const unsigned short* __restrict__ qb,
                 const unsigned short* __restrict__ kb,
                 const unsigned short* __restrict__ vtb,
                 float* __restrict__ out)
{
    // overlay: ps (18.4 KB, K-loop) shares space with oc (34.8 KB, combine)
    __shared__ char smem[8 * 16 * 68 * 4 + 8 * 2 * 16 * 4];   // 35.8 KB
    unsigned short* ps = (unsigned short*)smem;               // [8][16*PSS]
    float* oc = (float*)smem;                                 // [8][16][68]
    float* ml = (float*)(smem + 8 * 16 * 68 * 4);             // [8][2][16]

    const int tid  = threadIdx.x;
    const int g    = tid >> 6;        // wave = split-K group
    const int lane = tid & 63;
    const int quad = lane >> 4;
    const int col  = lane & 15;
    const int b    = blockIdx.x & 7;  // batch -> XCD pinning
    const int p    = blockIdx.x >> 3; // 0..63

    const unsigned short* qbb = qb  + (long)b * T_ * H_;
    const unsigned short* kbb = kb  + (long)b * T_ * H_;
    const unsigned short* vbb = vtb + (long)b * H_ * T_;

    for (int half = 0; half < 2; ++half) {
        const int qt = half ? (127 - p) : p;          // 16-row q-tile index
        const int nt = (qt + 4) >> 2;                 // ceil((qt+1)/4) key tiles

        bf16x8 qa0 = *(const bf16x8*)&qbb[(qt * 16 + col) * H_ + quad * 8];
        bf16x8 qa1 = *(const bf16x8*)&qbb[(qt * 16 + col) * H_ + 32 + quad * 8];

        f32x4 o[4];
        float m_i[4], l_i[4];
#pragma unroll
        for (int n = 0; n < 4; ++n) o[n] = (f32x4){0.f, 0.f, 0.f, 0.f};
#pragma unroll
        for (int r = 0; r < 4; ++r) { m_i[r] = -1e30f; l_i[r] = 0.f; }

        // K fragment prefetch for first tile
        bf16x8 kf[8];
        if (g < nt) {
#pragma unroll
            for (int kt = 0; kt < 4; ++kt) {
                const unsigned short* kp = kbb + ((long)(g * 64 + kt * 16 + col)) * H_ + quad * 8;
                kf[kt * 2]     = *(const bf16x8*)kp;
                kf[kt * 2 + 1] = *(const bf16x8*)(kp + 32);
            }
        }

        for (int s = g; s < nt; s += 8) {
            // S = Q K^T from prefetched fragments
            f32x4 sa[4];
#pragma unroll
            for (int kt = 0; kt < 4; ++kt) {
                sa[kt] = (f32x4){0.f, 0.f, 0.f, 0.f};
                sa[kt] = __builtin_amdgcn_mfma_f32_16x16x32_bf16(qa0, kf[kt * 2],     sa[kt], 0, 0, 0);
                sa[kt] = __builtin_amdgcn_mfma_f32_16x16x32_bf16(qa1, kf[kt * 2 + 1], sa[kt], 0, 0, 0);
            }

            // hoist V(s) loads: ~softmax-duration ahead of the PV use
            bf16x8 vf[8];
#pragma unroll
            for (int n = 0; n < 4; ++n) {
                const unsigned short* vp = vbb + ((long)(n * 16 + col)) * T_ + s * 64 + quad * 8;
                vf[n * 2]     = *(const bf16x8*)vp;
                vf[n * 2 + 1] = *(const bf16x8*)(vp + 32);
            }

            // prefetch next tile's K (overlaps softmax + PV below)
            if (s + 8 < nt) {
#pragma unroll
                for (int kt = 0; kt < 4; ++kt) {
                    const unsigned short* kp = kbb + ((long)((s + 8) * 64 + kt * 16 + col)) * H_ + quad * 8;
                    kf[kt * 2]     = *(const bf16x8*)kp;
                    kf[kt * 2 + 1] = *(const bf16x8*)(kp + 32);
                }
            }

            if (s == nt - 1) {            // diagonal tile: causal mask
#pragma unroll
                for (int kt = 0; kt < 4; ++kt) {
                    int kg = s * 64 + kt * 16 + col;
#pragma unroll
                    for (int r = 0; r < 4; ++r) {
                        int qg = qt * 16 + quad * 4 + r;
                        if (kg > qg) sa[kt][r] = -1e30f;
                    }
                }
            }

            // online softmax (exp2 domain; scale folded into Wq)
            float mx[4];
#pragma unroll
            for (int r = 0; r < 4; ++r)
                mx[r] = fmaxf(fmaxf(sa[0][r], sa[1][r]), fmaxf(sa[2][r], sa[3][r]));
#pragma unroll
            for (int off = 1; off < 16; off <<= 1)
#pragma unroll
                for (int r = 0; r < 4; ++r)
                    mx[r] = fmaxf(mx[r], __shfl_xor(mx[r], off, 64));

            float alpha[4], mnew[4];
#pragma unroll
            for (int r = 0; r < 4; ++r) {
                mnew[r]  = fmaxf(m_i[r], mx[r]);
                alpha[r] = __builtin_amdgcn_exp2f(m_i[r] - mnew[r]);
                m_i[r]   = mnew[r];
            }

            float rs[4] = {0.f, 0.f, 0.f, 0.f};
#pragma unroll
            for (int kt = 0; kt < 4; ++kt)
#pragma unroll
                for (int r = 0; r < 4; ++r) {
                    float pv = __builtin_amdgcn_exp2f(sa[kt][r] - mnew[r]);
                    rs[r] += pv;
                    ps[g * 16 * PSS + (quad * 4 + r) * PSS + kt * 16 + col] = f2bfu(pv);
                }
#pragma unroll
            for (int off = 1; off < 16; off <<= 1)
#pragma unroll
                for (int r = 0; r < 4; ++r)
                    rs[r] += __shfl_xor(rs[r], off, 64);
#pragma unroll
            for (int r = 0; r < 4; ++r)
                l_i[r] = l_i[r] * alpha[r] + rs[r];

#pragma unroll
            for (int n = 0; n < 4; ++n)
#pragma unroll
                for (int r = 0; r < 4; ++r)
                    o[n][r] *= alpha[r];

            // O += P @ V : P from per-wave LDS (A-layout), V already in regs
            bf16x8 pa0 = *(const bf16x8*)&ps[g * 16 * PSS + col * PSS + quad * 8];
            bf16x8 pa1 = *(const bf16x8*)&ps[g * 16 * PSS + col * PSS + 32 + quad * 8];
#pragma unroll
            for (int n = 0; n < 4; ++n) {
                o[n] = __builtin_amdgcn_mfma_f32_16x16x32_bf16(pa0, vf[n * 2],     o[n], 0, 0, 0);
                o[n] = __builtin_amdgcn_mfma_f32_16x16x32_bf16(pa1, vf[n * 2 + 1], o[n], 0, 0, 0);
            }
        }

        // ---- split-K combine (oc overlays ps -> barrier first) ----
        __syncthreads();
#pragma unroll
        for (int r = 0; r < 4; ++r) {
            int row = quad * 4 + r;
#pragma unroll
            for (int n = 0; n < 4; ++n)
                oc[(g * 16 + row) * 68 + n * 16 + col] = o[n][r];
        }
        if (col == 0) {
#pragma unroll
            for (int r = 0; r < 4; ++r) {
                ml[(g * 2 + 0) * 16 + quad * 4 + r] = m_i[r];
                ml[(g * 2 + 1) * 16 + quad * 4 + r] = l_i[r];
            }
        }
        __syncthreads();

        // merge: wave g owns q-rows 2g, 2g+1; lane = h (0..63)
#pragma unroll
        for (int rr = 0; rr < 2; ++rr) {
            int row = g * 2 + rr;
            float M = ml[0 * 32 + row];
#pragma unroll
            for (int j = 1; j < 8; ++j) M = fmaxf(M, ml[j * 32 + row]);
            float lsum = 0.f, osum = 0.f;
#pragma unroll
            for (int j = 0; j < 8; ++j) {
                float wgt = __builtin_amdgcn_exp2f(ml[j * 32 + row] - M);
                lsum += ml[j * 32 + 16 + row] * wgt;
                osum += oc[(j * 16 + row) * 68 + lane] * wgt;
            }
            out[((long)b * T_ + qt * 16 + row) * H_ + lane] = osum / lsum;
        }
        __syncthreads();   // before next half reuses ps/oc/ml
    }
}

extern "C" void kernel_launch(void* const* d_in, const int* in_sizes, int n_in,
                              void* d_out, int out_size, void* d_ws, size_t ws_size,
                              hipStream_t stream) {
    (void)in_sizes; (void)n_in; (void)out_size; (void)ws_size;
    const float* x  = (const float*)d_in[0];
    const float* Wq = (const float*)d_in[1];
    const float* Wk = (const float*)d_in[2];
    const float* Wv = (const float*)d_in[3];

    unsigned short* qb  = (unsigned short*)d_ws;               // 2 MB
    unsigned short* kb  = qb + (size_t)BT_ * H_;               // 2 MB
    unsigned short* vtb = kb + (size_t)BT_ * H_;               // 2 MB
    unsigned short* wf  = vtb + (size_t)BT_ * H_;              // 384 KB

    wprep_kernel<<<96, 256, 0, stream>>>(Wq, Wk, Wv, wf);
    qkv_kernel<<<BT_ / 16, 256, 0, stream>>>(x, wf, qb, kb, vtb);
    attn_kernel<<<B_ * 64, 512, 0, stream>>>(qb, kb, vtb, (float*)d_out);
}